// Round 27
// baseline (391.576 us; speedup 1.0000x reference)
//
#include <hip/hip_runtime.h>
#include <math.h>

#define S_LEN 2048
#define H_DIM 1024
#define NHQ 16
#define D_HEAD 64
#define FF_DIM 4096
#define NLAYER 2
#define EPSV 1e-6f
#define QKV_N 1152   // 1024 q + 64 k + 64 v

// converted-weight arena offsets (elements, compile-time)
#define WQ_OFF 0L
#define WK_OFF 1048576L
#define WV_OFF 1114112L
#define WO_OFF 1179648L
#define WG_OFF 2228224L
#define WU_OFF 6422528L
#define WD_OFF 10616832L
#define W_TOTAL 14811136L

typedef unsigned short ushortt;
typedef __attribute__((ext_vector_type(8))) short bf16x8;
typedef __attribute__((ext_vector_type(4))) float f32x4;
typedef __attribute__((ext_vector_type(16))) float f32x16;

__device__ __forceinline__ float bf2f(ushortt u) {
    union { float f; unsigned u; } c; c.u = ((unsigned)u) << 16; return c.f;
}
__device__ __forceinline__ ushortt f2bf(float f) {
    union { float f; unsigned u; } c; c.f = f;
    unsigned r = c.u + 0x7fff + ((c.u >> 16) & 1);
    return (ushortt)(r >> 16);
}
__device__ __forceinline__ unsigned cvtpk(float a, float b) {
    unsigned r;
    asm("v_cvt_pk_bf16_f32 %0, %1, %2" : "=v"(r) : "v"(a), "v"(b));
    return r;
}
__device__ __forceinline__ bf16x8 mk8(unsigned a, unsigned b, unsigned c, unsigned d) {
    union { unsigned u[4]; bf16x8 v; } t; t.u[0] = a; t.u[1] = b; t.u[2] = c; t.u[3] = d; return t.v;
}

__device__ __forceinline__ void gload_lds16(const ushortt* g, ushortt* l) {
    __builtin_amdgcn_global_load_lds(
        (const __attribute__((address_space(1))) unsigned int*)g,
        (__attribute__((address_space(3))) unsigned int*)l, 16, 0, 0);
}

// ---------------- all-weights f32 -> bf16 convert, one launch per layer ----------------
__global__ __launch_bounds__(256) void convall_k(const float* __restrict__ q,
                                                 const float* __restrict__ k,
                                                 const float* __restrict__ v,
                                                 const float* __restrict__ o,
                                                 const float* __restrict__ g,
                                                 const float* __restrict__ u,
                                                 const float* __restrict__ d,
                                                 ushortt* __restrict__ out) {
    long i8 = ((long)blockIdx.x * 256 + threadIdx.x) * 8;
    if (i8 >= W_TOTAL) return;
    const float* src; long rel;
    if (i8 < WK_OFF)      { src = q; rel = i8 - WQ_OFF; }
    else if (i8 < WV_OFF) { src = k; rel = i8 - WK_OFF; }
    else if (i8 < WO_OFF) { src = v; rel = i8 - WV_OFF; }
    else if (i8 < WG_OFF) { src = o; rel = i8 - WO_OFF; }
    else if (i8 < WU_OFF) { src = g; rel = i8 - WG_OFF; }
    else if (i8 < WD_OFF) { src = u; rel = i8 - WU_OFF; }
    else                  { src = d; rel = i8 - WD_OFF; }
    f32x4 a = *(const f32x4*)&src[rel];
    f32x4 b = *(const f32x4*)&src[rel + 4];
    bf16x8 ov;
    #pragma unroll
    for (int j = 0; j < 4; j++) { ov[j] = (short)f2bf(a[j]); ov[4 + j] = (short)f2bf(b[j]); }
    *(bf16x8*)&out[i8] = ov;
}

// ---------------- rmsnorm (optionally fused with embedding gather) ----------------
template <int GATHER>
__global__ __launch_bounds__(256) void rmsnorm_k(const int* __restrict__ ids,
                                                 const float* __restrict__ emb,
                                                 float* __restrict__ x,
                                                 const float* __restrict__ w,
                                                 ushortt* __restrict__ out) {
    __shared__ float red[4];
    int row = blockIdx.x, tid = threadIdx.x;
    f32x4 v;
    if (GATHER) {
        long id = ids[row];
        v = *((const f32x4*)emb + id * (H_DIM / 4) + tid);
        *(f32x4*)&x[(long)row * H_DIM + tid * 4] = v;
    } else {
        v = *(const f32x4*)&x[(long)row * H_DIM + tid * 4];
    }
    float ss = v[0]*v[0] + v[1]*v[1] + v[2]*v[2] + v[3]*v[3];
    #pragma unroll
    for (int off = 1; off < 64; off <<= 1) ss += __shfl_xor(ss, off, 64);
    if ((tid & 63) == 0) red[tid >> 6] = ss;
    __syncthreads();
    float tot = red[0] + red[1] + red[2] + red[3];
    float rs = rsqrtf(tot / (float)H_DIM + EPSV);
    f32x4 wv = *(const f32x4*)&w[tid * 4];
    #pragma unroll
    for (int j = 0; j < 4; j++)
        out[(long)row * H_DIM + tid * 4 + j] = f2bf(v[j] * rs * wv[j]);
}

// ---------------- GEMM 64x64, BK=64, 2-phase dbuf, swizzled LDS (r13/r17-proven) ----
// EPI 0: bf16 out; 1: f32 out += (atomic when SPLITK>1); 2: f32 out = resid + acc
// SPLITK: blockIdx.z covers K-range [z*K/SPLITK, (z+1)*K/SPLITK).
template <int EPI, int SPLITK>
__global__ __launch_bounds__(256) void gemm64(const ushortt* __restrict__ A,
                                              const ushortt* __restrict__ B,
                                              void* __restrict__ out,
                                              const float* __restrict__ resid,
                                              int M, int N, int K, int lda) {
    __shared__ ushortt As[2][64 * 64];
    __shared__ ushortt Bs[2][64 * 64];
    const int tid = threadIdx.x;
    const int lane = tid & 63;
    const int w = tid >> 6;
    const int wm = w >> 1, wn = w & 1;
    const int m0 = blockIdx.y * 64, n0 = blockIdx.x * 64;
    const int kz = (SPLITK > 1) ? blockIdx.z * (K / SPLITK) : 0;
    const int r15 = lane & 15, g = lane >> 4;

    const int sr = tid >> 3;
    const int scel = (tid & 7) * 8;
    const int swz = ((sr & 7) << 3);
    const int srcel = scel ^ swz;

    const ushortt* pa0 = &A[(long)(m0 + sr) * lda + kz + srcel];
    const ushortt* pa1 = &A[(long)(m0 + 32 + sr) * lda + kz + srcel];
    const ushortt* pb0 = &B[(long)(n0 + sr) * K + kz + srcel];
    const ushortt* pb1 = &B[(long)(n0 + 32 + sr) * K + kz + srcel];
    const int l0 = sr * 64 + scel, l1 = (32 + sr) * 64 + scel;

    f32x4 acc[2][2] = {};

#define STAGE(buf, t)                              \
    do {                                           \
        int kk_ = (t) * 64;                        \
        gload_lds16(pa0 + kk_, &As[buf][l0]);      \
        gload_lds16(pa1 + kk_, &As[buf][l1]);      \
        gload_lds16(pb0 + kk_, &Bs[buf][l0]);      \
        gload_lds16(pb1 + kk_, &Bs[buf][l1]);      \
    } while (0)

    STAGE(0, 0);
    asm volatile("s_waitcnt vmcnt(0)" : : : "memory");
    __builtin_amdgcn_s_barrier();

    const int NT = (K / SPLITK) / 64;
    int cur = 0;
    for (int t = 0; t < NT; ++t) {
        if (t + 1 < NT) STAGE(cur ^ 1, t + 1);

        bf16x8 a[2][2], b[2][2];
        #pragma unroll
        for (int mf = 0; mf < 2; mf++)
            #pragma unroll
            for (int ks = 0; ks < 2; ks++) {
                int row = wm * 32 + mf * 16 + r15;
                a[mf][ks] = *(bf16x8*)&As[cur][row * 64 + ((ks * 32 + g * 8) ^ ((row & 7) << 3))];
            }
        #pragma unroll
        for (int nf = 0; nf < 2; nf++)
            #pragma unroll
            for (int ks = 0; ks < 2; ks++) {
                int row = wn * 32 + nf * 16 + r15;
                b[nf][ks] = *(bf16x8*)&Bs[cur][row * 64 + ((ks * 32 + g * 8) ^ ((row & 7) << 3))];
            }
        #pragma unroll
        for (int ks = 0; ks < 2; ks++)
            #pragma unroll
            for (int mf = 0; mf < 2; mf++)
                #pragma unroll
                for (int nf = 0; nf < 2; nf++)
                    acc[mf][nf] = __builtin_amdgcn_mfma_f32_16x16x32_bf16(
                        a[mf][ks], b[nf][ks], acc[mf][nf], 0, 0, 0);

        asm volatile("s_waitcnt vmcnt(0)" : : : "memory");
        __builtin_amdgcn_s_barrier();
        cur ^= 1;
    }
#undef STAGE

    #pragma unroll
    for (int mf = 0; mf < 2; mf++)
        #pragma unroll
        for (int nf = 0; nf < 2; nf++)
            #pragma unroll
            for (int r = 0; r < 4; r++) {
                int row = m0 + wm * 32 + mf * 16 + g * 4 + r;
                int col = n0 + wn * 32 + nf * 16 + r15;
                float v = acc[mf][nf][r];
                long idx = (long)row * N + col;
                if (EPI == 0) ((ushortt*)out)[idx] = f2bf(v);
                else if (EPI == 1) {
                    if (SPLITK > 1) unsafeAtomicAdd(&((float*)out)[idx], v);
                    else ((float*)out)[idx] += v;
                } else ((float*)out)[idx] = resid[idx] + v;
            }
}

// ---------------- post-QKV: rope(k) + V, both packed into MFMA-fragment order -------
__global__ __launch_bounds__(256) void postqkv_k(const ushortt* __restrict__ qkv,
                                                 ushortt* __restrict__ kp,
                                                 ushortt* __restrict__ vp) {
    __shared__ ushortt t[64][66];
    const int b = blockIdx.x, tid = threadIdx.x;
    if (b < 32) {
        int idx = b * 256 + tid;          // over S*4
        int c = idx & 3;
        int s = idx >> 2;
        const ushortt* src = &qkv[(long)s * QKV_N + NHQ * D_HEAD + c * 8];
        bf16x8 X1 = *(const bf16x8*)src;
        bf16x8 X2 = *(const bf16x8*)(src + 32);
        bf16x8 LO, HI;
        #pragma unroll
        for (int j = 0; j < 8; j++) {
            int i = c * 8 + j;
            float fr = expf(-(float)i * 0.28782314f);  // 10000^(-i/32)
            float ang = (float)s * fr;
            float sn, cs;
            sincosf(ang, &sn, &cs);
            float x1 = bf2f((ushortt)X1[j]), x2 = bf2f((ushortt)X2[j]);
            LO[j] = (short)f2bf(x1 * cs - x2 * sn);
            HI[j] = (short)f2bf(x2 * cs + x1 * sn);
        }
        long base = (long)(s >> 5) * 2048;
        int lane = (s & 31) + 32 * (c & 1);
        *(bf16x8*)&kp[base + (long)(c >> 1) * 512 + lane * 8] = LO;
        *(bf16x8*)&kp[base + (long)(2 + (c >> 1)) * 512 + lane * 8] = HI;
    } else {
        int s0 = (b - 32) * 64;
        int grp = tid >> 6, lane = tid & 63;
        #pragma unroll
        for (int i = 0; i < 16; i++) {
            int r = grp * 16 + i;
            t[r][lane] = qkv[(long)(s0 + r) * QKV_N + NHQ * D_HEAD + D_HEAD + lane];
        }
        __syncthreads();
        #pragma unroll
        for (int cc = 0; cc < 2; cc++) {
            int ch = cc * 256 + tid;
            int tile_local = ch >> 8;
            int tt = (ch >> 6) & 3;
            int lo = ch & 63;
            int rbase = tile_local * 32 + (tt & 1) * 16 + (lo >> 5) * 8;
            int col = (tt >> 1) * 32 + (lo & 31);
            bf16x8 V8;
            #pragma unroll
            for (int j = 0; j < 8; j++) V8[j] = (short)t[rbase + j][col];
            *(bf16x8*)&vp[((long)(s0 >> 5) + tile_local) * 2048 + (long)tt * 512 + lo * 8] = V8;
        }
    }
}

// ---------------- attention: fragment-packed K/V (coalesced loads), exp2 softmax ----
__device__ __forceinline__ void attn_body32(const bf16x8 ka[4], const bf16x8 va[4],
                                            const bf16x8 bq[4],
                                            f32x16& O0, f32x16& O1,
                                            float& lrun) {
    f32x16 s = {};
    __builtin_amdgcn_s_setprio(1);
    #pragma unroll
    for (int ds = 0; ds < 4; ds++)
        s = __builtin_amdgcn_mfma_f32_32x32x16_bf16(ka[ds], bq[ds], s, 0, 0, 0);
    __builtin_amdgcn_s_setprio(0);

    float p[16];
    #pragma unroll
    for (int i = 0; i < 16; i++) p[i] = exp2f(s[i]);   // scale folded into Q
    float t0 = (p[0] + p[1]) + (p[2] + p[3]);
    float t1 = (p[4] + p[5]) + (p[6] + p[7]);
    float t2 = (p[8] + p[9]) + (p[10] + p[11]);
    float t3 = (p[12] + p[13]) + (p[14] + p[15]);
    lrun += (t0 + t1) + (t2 + t3);

    unsigned w0 = cvtpk(p[0], p[1]),  w1 = cvtpk(p[2], p[3]);
    unsigned w2 = cvtpk(p[4], p[5]),  w3 = cvtpk(p[6], p[7]);
    unsigned w4 = cvtpk(p[8], p[9]),  w5 = cvtpk(p[10], p[11]);
    unsigned w6 = cvtpk(p[12], p[13]), w7 = cvtpk(p[14], p[15]);
    asm volatile("v_permlane32_swap_b32 %0, %1" : "+v"(w0), "+v"(w2));
    asm volatile("v_permlane32_swap_b32 %0, %1" : "+v"(w1), "+v"(w3));
    asm volatile("v_permlane32_swap_b32 %0, %1" : "+v"(w4), "+v"(w6));
    asm volatile("v_permlane32_swap_b32 %0, %1" : "+v"(w5), "+v"(w7));
    bf16x8 B0 = mk8(w0, w1, w2, w3);
    bf16x8 B1 = mk8(w4, w5, w6, w7);

    __builtin_amdgcn_s_setprio(1);
    O0 = __builtin_amdgcn_mfma_f32_32x32x16_bf16(va[0], B0, O0, 0, 0, 0);
    O0 = __builtin_amdgcn_mfma_f32_32x32x16_bf16(va[1], B1, O0, 0, 0, 0);
    O1 = __builtin_amdgcn_mfma_f32_32x32x16_bf16(va[2], B0, O1, 0, 0, 0);
    O1 = __builtin_amdgcn_mfma_f32_32x32x16_bf16(va[3], B1, O1, 0, 0, 0);
    __builtin_amdgcn_s_setprio(0);
}

__global__ __launch_bounds__(256) void attn4_k(const ushortt* __restrict__ qkv,
                                               const ushortt* __restrict__ kp,
                                               const ushortt* __restrict__ vp,
                                               ushortt* __restrict__ o) {
    __shared__ ushortt Olds[4][32][72];
    __shared__ float Llds[4][32];
    const int tid = threadIdx.x;
    const int w = tid >> 6;
    const int lane = tid & 63;
    const int l31 = lane & 31, hb = lane >> 5;
    const int h = blockIdx.y;
    const int q0 = blockIdx.x * 32;

    bf16x8 bq[4];
    #pragma unroll
    for (int ds = 0; ds < 4; ds++)
        bq[ds] = *(const bf16x8*)&qkv[(long)(q0 + l31) * QKV_N + h * D_HEAD + ds * 16 + hb * 8];
    {
        const float SC = 0.18033688f;  // 0.125 * log2(e)
        const float srow = (float)(q0 + l31);
        #pragma unroll
        for (int t = 0; t < 2; t++) {
            bf16x8 A = bq[t], B = bq[t + 2];
            bf16x8 An, Bn;
            #pragma unroll
            for (int j = 0; j < 8; j++) {
                int i = t * 16 + hb * 8 + j;
                float fr = expf(-(float)i * 0.28782314f);  // 10000^(-i/32)
                float ang = srow * fr;
                float sn, cs;
                sincosf(ang, &sn, &cs);
                float x1 = bf2f((ushortt)A[j]), x2 = bf2f((ushortt)B[j]);
                An[j] = (short)f2bf((x1 * cs - x2 * sn) * SC);
                Bn[j] = (short)f2bf((x2 * cs + x1 * sn) * SC);
            }
            bq[t] = An; bq[t + 2] = Bn;
        }
    }

#define LOADKV(KA, VA, J0)                                                          \
    do {                                                                            \
        long tb_ = (long)((J0) >> 5) * 2048 + lane * 8;                             \
        _Pragma("unroll") for (int ds = 0; ds < 4; ds++)                            \
            KA[ds] = *(const bf16x8*)&kp[tb_ + ds * 512];                           \
        _Pragma("unroll") for (int t = 0; t < 4; t++)                               \
            VA[t] = *(const bf16x8*)&vp[tb_ + t * 512];                             \
    } while (0)

    f32x16 OA0 = {}, OA1 = {}, OB0 = {}, OB1 = {};
    float lrunA = 0.f, lrunB = 0.f;

    const int jbeg = w * (S_LEN / 4);
    const int jend = jbeg + (S_LEN / 4);

    bf16x8 kaA[4], vaA[4], kaB[4], vaB[4];
    LOADKV(kaA, vaA, jbeg);
    for (int j0 = jbeg; j0 < jend; j0 += 64) {
        LOADKV(kaB, vaB, j0 + 32);
        attn_body32(kaA, vaA, bq, OA0, OA1, lrunA);
        if (j0 + 64 < jend) LOADKV(kaA, vaA, j0 + 64);
        attn_body32(kaB, vaB, bq, OB0, OB1, lrunB);
    }
#undef LOADKV

    f32x16 O0, O1;
    #pragma unroll
    for (int r = 0; r < 16; r++) { O0[r] = OA0[r] + OB0[r]; O1[r] = OA1[r] + OB1[r]; }
    float lrun = lrunA + lrunB;

    float ltot = lrun + __shfl_xor(lrun, 32, 64);
    #pragma unroll
    for (int r = 0; r < 16; r++) {
        int d = (r & 3) + 8 * (r >> 2) + 4 * hb;
        Olds[w][l31][d] = f2bf(O0[r]);
        Olds[w][l31][32 + d] = f2bf(O1[r]);
    }
    if (hb == 0) Llds[w][l31] = ltot;
    __syncthreads();

    const int q = tid >> 3, d0 = (tid & 7) * 8;
    float denom = Llds[0][q] + Llds[1][q] + Llds[2][q] + Llds[3][q];
    float inv = 1.f / denom;
    float acc[8] = {};
    #pragma unroll
    for (int z = 0; z < 4; z++) {
        bf16x8 t8 = *(bf16x8*)&Olds[z][q][d0];
        #pragma unroll
        for (int j = 0; j < 8; j++) acc[j] += bf2f((ushortt)t8[j]);
    }
    bf16x8 ov;
    #pragma unroll
    for (int j = 0; j < 8; j++) ov[j] = (short)f2bf(acc[j] * inv);
    *(bf16x8*)&o[(long)(q0 + q) * H_DIM + h * D_HEAD + d0] = ov;
}

// ---------------- silu: vectorized x8, compact output [S, FF_DIM] ----------------
__global__ __launch_bounds__(256) void silu_mul_k(const ushortt* __restrict__ gub,
                                                  ushortt* __restrict__ ffout, int n8) {
    int idx = blockIdx.x * 256 + threadIdx.x;   // over S*FF/8
    if (idx >= n8) return;
    int row = idx >> 9;
    int c8 = idx & (FF_DIM / 8 - 1);
    const ushortt* base = &gub[(long)row * (2 * FF_DIM) + c8 * 8];
    bf16x8 gv = *(const bf16x8*)base;
    bf16x8 uv = *(const bf16x8*)(base + FF_DIM);
    bf16x8 ov;
    #pragma unroll
    for (int j = 0; j < 8; j++) {
        float a = bf2f((ushortt)gv[j]);
        float b = bf2f((ushortt)uv[j]);
        ov[j] = (short)f2bf((a / (1.f + __expf(-a))) * b);
    }
    *(bf16x8*)&ffout[(long)row * FF_DIM + c8 * 8] = ov;
}

extern "C" void kernel_launch(void* const* d_in, const int* in_sizes, int n_in,
                              void* d_out, int out_size, void* d_ws, size_t ws_size,
                              hipStream_t stream) {
    const int* ids = (const int*)d_in[0];
    const float* emb = (const float*)d_in[1];
    const float* Wq = (const float*)d_in[2];
    const float* Wk = (const float*)d_in[3];
    const float* Wv = (const float*)d_in[4];
    const float* Wo = (const float*)d_in[5];
    const float* Wg = (const float*)d_in[6];
    const float* Wu = (const float*)d_in[7];
    const float* Wd = (const float*)d_in[8];
    const float* ln1 = (const float*)d_in[9];
    const float* ln2 = (const float*)d_in[10];

    char* ws = (char*)d_ws;
    float* x = (float*)ws;        ws += (size_t)S_LEN * H_DIM * 4;
    ushortt* qkv = (ushortt*)ws;  ws += (size_t)S_LEN * QKV_N * 2;
    ushortt* h = (ushortt*)ws;    ws += (size_t)S_LEN * H_DIM * 2;
    ushortt* kp = (ushortt*)ws;   ws += (size_t)S_LEN * D_HEAD * 2;   // packed K
    ushortt* vp = (ushortt*)ws;   ws += (size_t)S_LEN * D_HEAD * 2;   // packed V
    ushortt* ob = (ushortt*)ws;   ws += (size_t)S_LEN * H_DIM * 2;
    ushortt* gub = (ushortt*)ws;  ws += (size_t)S_LEN * 2 * FF_DIM * 2;  // [S, 8192]
    ushortt* ffout = (ushortt*)ws; ws += (size_t)S_LEN * FF_DIM * 2;     // [S, 4096]
    ushortt* wt = (ushortt*)ws;   ws += (size_t)W_TOTAL * 2;             // weight arena

    for (int l = 0; l < NLAYER; l++) {
        convall_k<<<(int)(W_TOTAL / 8 / 256), 256, 0, stream>>>(
            Wq + (long)l * H_DIM * H_DIM, Wk + (long)l * D_HEAD * H_DIM,
            Wv + (long)l * D_HEAD * H_DIM, Wo + (long)l * H_DIM * H_DIM,
            Wg + (long)l * FF_DIM * H_DIM, Wu + (long)l * FF_DIM * H_DIM,
            Wd + (long)l * H_DIM * FF_DIM, wt);

        if (l == 0)
            rmsnorm_k<1><<<S_LEN, 256, 0, stream>>>(ids, emb, x, ln1, h);
        else
            rmsnorm_k<0><<<S_LEN, 256, 0, stream>>>(ids, emb, x, ln1 + (long)l * H_DIM, h);

        gemm64<0, 1><<<dim3(QKV_N / 64, S_LEN / 64), 256, 0, stream>>>(
            h, wt + WQ_OFF, qkv, nullptr, S_LEN, QKV_N, H_DIM, H_DIM);

        postqkv_k<<<64, 256, 0, stream>>>(qkv, kp, vp);

        attn4_k<<<dim3(S_LEN / 32, NHQ), 256, 0, stream>>>(qkv, kp, vp, ob);

        // Wo: split-K x2 (N=1024 -> only 512 xy-blocks; z doubles occupancy)
        gemm64<1, 2><<<dim3(H_DIM / 64, S_LEN / 64, 2), 256, 0, stream>>>(
            ob, wt + WO_OFF, x, nullptr, S_LEN, H_DIM, H_DIM, H_DIM);

        rmsnorm_k<0><<<S_LEN, 256, 0, stream>>>(ids, emb, x, ln2 + (long)l * H_DIM, h);

        gemm64<0, 1><<<dim3(2 * FF_DIM / 64, S_LEN / 64), 256, 0, stream>>>(
            h, wt + WG_OFF, gub, nullptr, S_LEN, 2 * FF_DIM, H_DIM, H_DIM);
        silu_mul_k<<<(S_LEN * FF_DIM / 8 + 255) / 256, 256, 0, stream>>>(
            gub, ffout, S_LEN * FF_DIM / 8);

        if (l == NLAYER - 1)
            gemm64<2, 1><<<dim3(H_DIM / 64, S_LEN / 64), 256, 0, stream>>>(
                ffout, wt + WD_OFF, d_out, x, S_LEN, H_DIM, FF_DIM, FF_DIM);
        else
            gemm64<1, 2><<<dim3(H_DIM / 64, S_LEN / 64, 2), 256, 0, stream>>>(
                ffout, wt + WD_OFF, x, nullptr, S_LEN, H_DIM, FF_DIM, FF_DIM);
    }
}

// Round 28
// 384.320 us; speedup vs baseline: 1.0189x; 1.0189x over previous
//
#include <hip/hip_runtime.h>
#include <math.h>

#define S_LEN 2048
#define H_DIM 1024
#define NHQ 16
#define D_HEAD 64
#define FF_DIM 4096
#define NLAYER 2
#define EPSV 1e-6f
#define QKV_N 1152   // 1024 q + 64 k + 64 v

// converted-weight arena offsets (elements, compile-time)
#define WQ_OFF 0L
#define WK_OFF 1048576L
#define WV_OFF 1114112L
#define WO_OFF 1179648L
#define WG_OFF 2228224L
#define WU_OFF 6422528L
#define WD_OFF 10616832L
#define W_TOTAL 14811136L

typedef unsigned short ushortt;
typedef __attribute__((ext_vector_type(8))) short bf16x8;
typedef __attribute__((ext_vector_type(4))) float f32x4;
typedef __attribute__((ext_vector_type(16))) float f32x16;

__device__ __forceinline__ float bf2f(ushortt u) {
    union { float f; unsigned u; } c; c.u = ((unsigned)u) << 16; return c.f;
}
__device__ __forceinline__ ushortt f2bf(float f) {
    union { float f; unsigned u; } c; c.f = f;
    unsigned r = c.u + 0x7fff + ((c.u >> 16) & 1);
    return (ushortt)(r >> 16);
}
__device__ __forceinline__ unsigned cvtpk(float a, float b) {
    unsigned r;
    asm("v_cvt_pk_bf16_f32 %0, %1, %2" : "=v"(r) : "v"(a), "v"(b));
    return r;
}
__device__ __forceinline__ bf16x8 mk8(unsigned a, unsigned b, unsigned c, unsigned d) {
    union { unsigned u[4]; bf16x8 v; } t; t.u[0] = a; t.u[1] = b; t.u[2] = c; t.u[3] = d; return t.v;
}

__device__ __forceinline__ void gload_lds16(const ushortt* g, ushortt* l) {
    __builtin_amdgcn_global_load_lds(
        (const __attribute__((address_space(1))) unsigned int*)g,
        (__attribute__((address_space(3))) unsigned int*)l, 16, 0, 0);
}

// ---------------- all-weights f32 -> bf16 convert, one launch per layer ----------------
__global__ __launch_bounds__(256) void convall_k(const float* __restrict__ q,
                                                 const float* __restrict__ k,
                                                 const float* __restrict__ v,
                                                 const float* __restrict__ o,
                                                 const float* __restrict__ g,
                                                 const float* __restrict__ u,
                                                 const float* __restrict__ d,
                                                 ushortt* __restrict__ out) {
    long i8 = ((long)blockIdx.x * 256 + threadIdx.x) * 8;
    if (i8 >= W_TOTAL) return;
    const float* src; long rel;
    if (i8 < WK_OFF)      { src = q; rel = i8 - WQ_OFF; }
    else if (i8 < WV_OFF) { src = k; rel = i8 - WK_OFF; }
    else if (i8 < WO_OFF) { src = v; rel = i8 - WV_OFF; }
    else if (i8 < WG_OFF) { src = o; rel = i8 - WO_OFF; }
    else if (i8 < WU_OFF) { src = g; rel = i8 - WG_OFF; }
    else if (i8 < WD_OFF) { src = u; rel = i8 - WU_OFF; }
    else                  { src = d; rel = i8 - WD_OFF; }
    f32x4 a = *(const f32x4*)&src[rel];
    f32x4 b = *(const f32x4*)&src[rel + 4];
    bf16x8 ov;
    #pragma unroll
    for (int j = 0; j < 4; j++) { ov[j] = (short)f2bf(a[j]); ov[4 + j] = (short)f2bf(b[j]); }
    *(bf16x8*)&out[i8] = ov;
}

// ---------------- rmsnorm (optionally fused with embedding gather) ----------------
template <int GATHER>
__global__ __launch_bounds__(256) void rmsnorm_k(const int* __restrict__ ids,
                                                 const float* __restrict__ emb,
                                                 float* __restrict__ x,
                                                 const float* __restrict__ w,
                                                 ushortt* __restrict__ out) {
    __shared__ float red[4];
    int row = blockIdx.x, tid = threadIdx.x;
    f32x4 v;
    if (GATHER) {
        long id = ids[row];
        v = *((const f32x4*)emb + id * (H_DIM / 4) + tid);
        *(f32x4*)&x[(long)row * H_DIM + tid * 4] = v;
    } else {
        v = *(const f32x4*)&x[(long)row * H_DIM + tid * 4];
    }
    float ss = v[0]*v[0] + v[1]*v[1] + v[2]*v[2] + v[3]*v[3];
    #pragma unroll
    for (int off = 1; off < 64; off <<= 1) ss += __shfl_xor(ss, off, 64);
    if ((tid & 63) == 0) red[tid >> 6] = ss;
    __syncthreads();
    float tot = red[0] + red[1] + red[2] + red[3];
    float rs = rsqrtf(tot / (float)H_DIM + EPSV);
    f32x4 wv = *(const f32x4*)&w[tid * 4];
    #pragma unroll
    for (int j = 0; j < 4; j++)
        out[(long)row * H_DIM + tid * 4 + j] = f2bf(v[j] * rs * wv[j]);
}

// ---------------- GEMM 64x64, BK=64, 2-phase dbuf, swizzled LDS (r13/r17-proven) ----
// EPI 0: bf16 out; 1: f32 out += ; 2: f32 out = resid + acc
// NOTE r27 post-mortem: split-K x2 REVERTED (doubled B-panel fetch + atomic RMW
// cost > occupancy gain; 386->392us). Natural grid, SPLITK=1 is the optimum here.
template <int EPI>
__global__ __launch_bounds__(256) void gemm64(const ushortt* __restrict__ A,
                                              const ushortt* __restrict__ B,
                                              void* __restrict__ out,
                                              const float* __restrict__ resid,
                                              int M, int N, int K, int lda) {
    __shared__ ushortt As[2][64 * 64];
    __shared__ ushortt Bs[2][64 * 64];
    const int tid = threadIdx.x;
    const int lane = tid & 63;
    const int w = tid >> 6;
    const int wm = w >> 1, wn = w & 1;
    const int m0 = blockIdx.y * 64, n0 = blockIdx.x * 64;
    const int r15 = lane & 15, g = lane >> 4;

    const int sr = tid >> 3;
    const int scel = (tid & 7) * 8;
    const int swz = ((sr & 7) << 3);
    const int srcel = scel ^ swz;

    const ushortt* pa0 = &A[(long)(m0 + sr) * lda + srcel];
    const ushortt* pa1 = &A[(long)(m0 + 32 + sr) * lda + srcel];
    const ushortt* pb0 = &B[(long)(n0 + sr) * K + srcel];
    const ushortt* pb1 = &B[(long)(n0 + 32 + sr) * K + srcel];
    const int l0 = sr * 64 + scel, l1 = (32 + sr) * 64 + scel;

    f32x4 acc[2][2] = {};

#define STAGE(buf, t)                              \
    do {                                           \
        int kk_ = (t) * 64;                        \
        gload_lds16(pa0 + kk_, &As[buf][l0]);      \
        gload_lds16(pa1 + kk_, &As[buf][l1]);      \
        gload_lds16(pb0 + kk_, &Bs[buf][l0]);      \
        gload_lds16(pb1 + kk_, &Bs[buf][l1]);      \
    } while (0)

    STAGE(0, 0);
    asm volatile("s_waitcnt vmcnt(0)" : : : "memory");
    __builtin_amdgcn_s_barrier();

    const int NT = K / 64;
    int cur = 0;
    for (int t = 0; t < NT; ++t) {
        if (t + 1 < NT) STAGE(cur ^ 1, t + 1);

        bf16x8 a[2][2], b[2][2];
        #pragma unroll
        for (int mf = 0; mf < 2; mf++)
            #pragma unroll
            for (int ks = 0; ks < 2; ks++) {
                int row = wm * 32 + mf * 16 + r15;
                a[mf][ks] = *(bf16x8*)&As[cur][row * 64 + ((ks * 32 + g * 8) ^ ((row & 7) << 3))];
            }
        #pragma unroll
        for (int nf = 0; nf < 2; nf++)
            #pragma unroll
            for (int ks = 0; ks < 2; ks++) {
                int row = wn * 32 + nf * 16 + r15;
                b[nf][ks] = *(bf16x8*)&Bs[cur][row * 64 + ((ks * 32 + g * 8) ^ ((row & 7) << 3))];
            }
        #pragma unroll
        for (int ks = 0; ks < 2; ks++)
            #pragma unroll
            for (int mf = 0; mf < 2; mf++)
                #pragma unroll
                for (int nf = 0; nf < 2; nf++)
                    acc[mf][nf] = __builtin_amdgcn_mfma_f32_16x16x32_bf16(
                        a[mf][ks], b[nf][ks], acc[mf][nf], 0, 0, 0);

        asm volatile("s_waitcnt vmcnt(0)" : : : "memory");
        __builtin_amdgcn_s_barrier();
        cur ^= 1;
    }
#undef STAGE

    #pragma unroll
    for (int mf = 0; mf < 2; mf++)
        #pragma unroll
        for (int nf = 0; nf < 2; nf++)
            #pragma unroll
            for (int r = 0; r < 4; r++) {
                int row = m0 + wm * 32 + mf * 16 + g * 4 + r;
                int col = n0 + wn * 32 + nf * 16 + r15;
                float v = acc[mf][nf][r];
                long idx = (long)row * N + col;
                if (EPI == 0) ((ushortt*)out)[idx] = f2bf(v);
                else if (EPI == 1) ((float*)out)[idx] += v;
                else ((float*)out)[idx] = resid[idx] + v;
            }
}

// ---------------- post-QKV: rope(k) + V, both packed into MFMA-fragment order -------
__global__ __launch_bounds__(256) void postqkv_k(const ushortt* __restrict__ qkv,
                                                 ushortt* __restrict__ kp,
                                                 ushortt* __restrict__ vp) {
    __shared__ ushortt t[64][66];
    const int b = blockIdx.x, tid = threadIdx.x;
    if (b < 32) {
        int idx = b * 256 + tid;          // over S*4
        int c = idx & 3;
        int s = idx >> 2;
        const ushortt* src = &qkv[(long)s * QKV_N + NHQ * D_HEAD + c * 8];
        bf16x8 X1 = *(const bf16x8*)src;
        bf16x8 X2 = *(const bf16x8*)(src + 32);
        bf16x8 LO, HI;
        #pragma unroll
        for (int j = 0; j < 8; j++) {
            int i = c * 8 + j;
            float fr = expf(-(float)i * 0.28782314f);  // 10000^(-i/32)
            float ang = (float)s * fr;
            float sn, cs;
            sincosf(ang, &sn, &cs);
            float x1 = bf2f((ushortt)X1[j]), x2 = bf2f((ushortt)X2[j]);
            LO[j] = (short)f2bf(x1 * cs - x2 * sn);
            HI[j] = (short)f2bf(x2 * cs + x1 * sn);
        }
        long base = (long)(s >> 5) * 2048;
        int lane = (s & 31) + 32 * (c & 1);
        *(bf16x8*)&kp[base + (long)(c >> 1) * 512 + lane * 8] = LO;
        *(bf16x8*)&kp[base + (long)(2 + (c >> 1)) * 512 + lane * 8] = HI;
    } else {
        int s0 = (b - 32) * 64;
        int grp = tid >> 6, lane = tid & 63;
        #pragma unroll
        for (int i = 0; i < 16; i++) {
            int r = grp * 16 + i;
            t[r][lane] = qkv[(long)(s0 + r) * QKV_N + NHQ * D_HEAD + D_HEAD + lane];
        }
        __syncthreads();
        #pragma unroll
        for (int cc = 0; cc < 2; cc++) {
            int ch = cc * 256 + tid;
            int tile_local = ch >> 8;
            int tt = (ch >> 6) & 3;
            int lo = ch & 63;
            int rbase = tile_local * 32 + (tt & 1) * 16 + (lo >> 5) * 8;
            int col = (tt >> 1) * 32 + (lo & 31);
            bf16x8 V8;
            #pragma unroll
            for (int j = 0; j < 8; j++) V8[j] = (short)t[rbase + j][col];
            *(bf16x8*)&vp[((long)(s0 >> 5) + tile_local) * 2048 + (long)tt * 512 + lo * 8] = V8;
        }
    }
}

// ---------------- attention: fragment-packed K/V (coalesced loads), exp2 softmax ----
__device__ __forceinline__ void attn_body32(const bf16x8 ka[4], const bf16x8 va[4],
                                            const bf16x8 bq[4],
                                            f32x16& O0, f32x16& O1,
                                            float& lrun) {
    f32x16 s = {};
    __builtin_amdgcn_s_setprio(1);
    #pragma unroll
    for (int ds = 0; ds < 4; ds++)
        s = __builtin_amdgcn_mfma_f32_32x32x16_bf16(ka[ds], bq[ds], s, 0, 0, 0);
    __builtin_amdgcn_s_setprio(0);

    float p[16];
    #pragma unroll
    for (int i = 0; i < 16; i++) p[i] = exp2f(s[i]);   // scale folded into Q
    float t0 = (p[0] + p[1]) + (p[2] + p[3]);
    float t1 = (p[4] + p[5]) + (p[6] + p[7]);
    float t2 = (p[8] + p[9]) + (p[10] + p[11]);
    float t3 = (p[12] + p[13]) + (p[14] + p[15]);
    lrun += (t0 + t1) + (t2 + t3);

    unsigned w0 = cvtpk(p[0], p[1]),  w1 = cvtpk(p[2], p[3]);
    unsigned w2 = cvtpk(p[4], p[5]),  w3 = cvtpk(p[6], p[7]);
    unsigned w4 = cvtpk(p[8], p[9]),  w5 = cvtpk(p[10], p[11]);
    unsigned w6 = cvtpk(p[12], p[13]), w7 = cvtpk(p[14], p[15]);
    asm volatile("v_permlane32_swap_b32 %0, %1" : "+v"(w0), "+v"(w2));
    asm volatile("v_permlane32_swap_b32 %0, %1" : "+v"(w1), "+v"(w3));
    asm volatile("v_permlane32_swap_b32 %0, %1" : "+v"(w4), "+v"(w6));
    asm volatile("v_permlane32_swap_b32 %0, %1" : "+v"(w5), "+v"(w7));
    bf16x8 B0 = mk8(w0, w1, w2, w3);
    bf16x8 B1 = mk8(w4, w5, w6, w7);

    __builtin_amdgcn_s_setprio(1);
    O0 = __builtin_amdgcn_mfma_f32_32x32x16_bf16(va[0], B0, O0, 0, 0, 0);
    O0 = __builtin_amdgcn_mfma_f32_32x32x16_bf16(va[1], B1, O0, 0, 0, 0);
    O1 = __builtin_amdgcn_mfma_f32_32x32x16_bf16(va[2], B0, O1, 0, 0, 0);
    O1 = __builtin_amdgcn_mfma_f32_32x32x16_bf16(va[3], B1, O1, 0, 0, 0);
    __builtin_amdgcn_s_setprio(0);
}

__global__ __launch_bounds__(256) void attn4_k(const ushortt* __restrict__ qkv,
                                               const ushortt* __restrict__ kp,
                                               const ushortt* __restrict__ vp,
                                               ushortt* __restrict__ o) {
    __shared__ ushortt Olds[4][32][72];
    __shared__ float Llds[4][32];
    const int tid = threadIdx.x;
    const int w = tid >> 6;
    const int lane = tid & 63;
    const int l31 = lane & 31, hb = lane >> 5;
    const int h = blockIdx.y;
    const int q0 = blockIdx.x * 32;

    bf16x8 bq[4];
    #pragma unroll
    for (int ds = 0; ds < 4; ds++)
        bq[ds] = *(const bf16x8*)&qkv[(long)(q0 + l31) * QKV_N + h * D_HEAD + ds * 16 + hb * 8];
    {
        const float SC = 0.18033688f;  // 0.125 * log2(e)
        const float srow = (float)(q0 + l31);
        #pragma unroll
        for (int t = 0; t < 2; t++) {
            bf16x8 A = bq[t], B = bq[t + 2];
            bf16x8 An, Bn;
            #pragma unroll
            for (int j = 0; j < 8; j++) {
                int i = t * 16 + hb * 8 + j;
                float fr = expf(-(float)i * 0.28782314f);  // 10000^(-i/32)
                float ang = srow * fr;
                float sn, cs;
                sincosf(ang, &sn, &cs);
                float x1 = bf2f((ushortt)A[j]), x2 = bf2f((ushortt)B[j]);
                An[j] = (short)f2bf((x1 * cs - x2 * sn) * SC);
                Bn[j] = (short)f2bf((x2 * cs + x1 * sn) * SC);
            }
            bq[t] = An; bq[t + 2] = Bn;
        }
    }

#define LOADKV(KA, VA, J0)                                                          \
    do {                                                                            \
        long tb_ = (long)((J0) >> 5) * 2048 + lane * 8;                             \
        _Pragma("unroll") for (int ds = 0; ds < 4; ds++)                            \
            KA[ds] = *(const bf16x8*)&kp[tb_ + ds * 512];                           \
        _Pragma("unroll") for (int t = 0; t < 4; t++)                               \
            VA[t] = *(const bf16x8*)&vp[tb_ + t * 512];                             \
    } while (0)

    f32x16 OA0 = {}, OA1 = {}, OB0 = {}, OB1 = {};
    float lrunA = 0.f, lrunB = 0.f;

    const int jbeg = w * (S_LEN / 4);
    const int jend = jbeg + (S_LEN / 4);

    bf16x8 kaA[4], vaA[4], kaB[4], vaB[4];
    LOADKV(kaA, vaA, jbeg);
    for (int j0 = jbeg; j0 < jend; j0 += 64) {
        LOADKV(kaB, vaB, j0 + 32);
        attn_body32(kaA, vaA, bq, OA0, OA1, lrunA);
        if (j0 + 64 < jend) LOADKV(kaA, vaA, j0 + 64);
        attn_body32(kaB, vaB, bq, OB0, OB1, lrunB);
    }
#undef LOADKV

    f32x16 O0, O1;
    #pragma unroll
    for (int r = 0; r < 16; r++) { O0[r] = OA0[r] + OB0[r]; O1[r] = OA1[r] + OB1[r]; }
    float lrun = lrunA + lrunB;

    float ltot = lrun + __shfl_xor(lrun, 32, 64);
    #pragma unroll
    for (int r = 0; r < 16; r++) {
        int d = (r & 3) + 8 * (r >> 2) + 4 * hb;
        Olds[w][l31][d] = f2bf(O0[r]);
        Olds[w][l31][32 + d] = f2bf(O1[r]);
    }
    if (hb == 0) Llds[w][l31] = ltot;
    __syncthreads();

    const int q = tid >> 3, d0 = (tid & 7) * 8;
    float denom = Llds[0][q] + Llds[1][q] + Llds[2][q] + Llds[3][q];
    float inv = 1.f / denom;
    float acc[8] = {};
    #pragma unroll
    for (int z = 0; z < 4; z++) {
        bf16x8 t8 = *(bf16x8*)&Olds[z][q][d0];
        #pragma unroll
        for (int j = 0; j < 8; j++) acc[j] += bf2f((ushortt)t8[j]);
    }
    bf16x8 ov;
    #pragma unroll
    for (int j = 0; j < 8; j++) ov[j] = (short)f2bf(acc[j] * inv);
    *(bf16x8*)&o[(long)(q0 + q) * H_DIM + h * D_HEAD + d0] = ov;
}

// ---------------- silu: vectorized x8, compact output [S, FF_DIM] ----------------
__global__ __launch_bounds__(256) void silu_mul_k(const ushortt* __restrict__ gub,
                                                  ushortt* __restrict__ ffout, int n8) {
    int idx = blockIdx.x * 256 + threadIdx.x;   // over S*FF/8
    if (idx >= n8) return;
    int row = idx >> 9;
    int c8 = idx & (FF_DIM / 8 - 1);
    const ushortt* base = &gub[(long)row * (2 * FF_DIM) + c8 * 8];
    bf16x8 gv = *(const bf16x8*)base;
    bf16x8 uv = *(const bf16x8*)(base + FF_DIM);
    bf16x8 ov;
    #pragma unroll
    for (int j = 0; j < 8; j++) {
        float a = bf2f((ushortt)gv[j]);
        float b = bf2f((ushortt)uv[j]);
        ov[j] = (short)f2bf((a / (1.f + __expf(-a))) * b);
    }
    *(bf16x8*)&ffout[(long)row * FF_DIM + c8 * 8] = ov;
}

extern "C" void kernel_launch(void* const* d_in, const int* in_sizes, int n_in,
                              void* d_out, int out_size, void* d_ws, size_t ws_size,
                              hipStream_t stream) {
    const int* ids = (const int*)d_in[0];
    const float* emb = (const float*)d_in[1];
    const float* Wq = (const float*)d_in[2];
    const float* Wk = (const float*)d_in[3];
    const float* Wv = (const float*)d_in[4];
    const float* Wo = (const float*)d_in[5];
    const float* Wg = (const float*)d_in[6];
    const float* Wu = (const float*)d_in[7];
    const float* Wd = (const float*)d_in[8];
    const float* ln1 = (const float*)d_in[9];
    const float* ln2 = (const float*)d_in[10];

    char* ws = (char*)d_ws;
    float* x = (float*)ws;        ws += (size_t)S_LEN * H_DIM * 4;
    ushortt* qkv = (ushortt*)ws;  ws += (size_t)S_LEN * QKV_N * 2;
    ushortt* h = (ushortt*)ws;    ws += (size_t)S_LEN * H_DIM * 2;
    ushortt* kp = (ushortt*)ws;   ws += (size_t)S_LEN * D_HEAD * 2;   // packed K
    ushortt* vp = (ushortt*)ws;   ws += (size_t)S_LEN * D_HEAD * 2;   // packed V
    ushortt* ob = (ushortt*)ws;   ws += (size_t)S_LEN * H_DIM * 2;
    ushortt* gub = (ushortt*)ws;  ws += (size_t)S_LEN * 2 * FF_DIM * 2;  // [S, 8192]
    ushortt* ffout = (ushortt*)ws; ws += (size_t)S_LEN * FF_DIM * 2;     // [S, 4096]
    ushortt* wt = (ushortt*)ws;   ws += (size_t)W_TOTAL * 2;             // weight arena

    for (int l = 0; l < NLAYER; l++) {
        convall_k<<<(int)(W_TOTAL / 8 / 256), 256, 0, stream>>>(
            Wq + (long)l * H_DIM * H_DIM, Wk + (long)l * D_HEAD * H_DIM,
            Wv + (long)l * D_HEAD * H_DIM, Wo + (long)l * H_DIM * H_DIM,
            Wg + (long)l * FF_DIM * H_DIM, Wu + (long)l * FF_DIM * H_DIM,
            Wd + (long)l * H_DIM * FF_DIM, wt);

        if (l == 0)
            rmsnorm_k<1><<<S_LEN, 256, 0, stream>>>(ids, emb, x, ln1, h);
        else
            rmsnorm_k<0><<<S_LEN, 256, 0, stream>>>(ids, emb, x, ln1 + (long)l * H_DIM, h);

        gemm64<0><<<dim3(QKV_N / 64, S_LEN / 64), 256, 0, stream>>>(
            h, wt + WQ_OFF, qkv, nullptr, S_LEN, QKV_N, H_DIM, H_DIM);

        postqkv_k<<<64, 256, 0, stream>>>(qkv, kp, vp);

        attn4_k<<<dim3(S_LEN / 32, NHQ), 256, 0, stream>>>(qkv, kp, vp, ob);

        gemm64<1><<<dim3(H_DIM / 64, S_LEN / 64), 256, 0, stream>>>(
            ob, wt + WO_OFF, x, nullptr, S_LEN, H_DIM, H_DIM, H_DIM);

        rmsnorm_k<0><<<S_LEN, 256, 0, stream>>>(ids, emb, x, ln2 + (long)l * H_DIM, h);

        gemm64<0><<<dim3(2 * FF_DIM / 64, S_LEN / 64), 256, 0, stream>>>(
            h, wt + WG_OFF, gub, nullptr, S_LEN, 2 * FF_DIM, H_DIM, H_DIM);
        silu_mul_k<<<(S_LEN * FF_DIM / 8 + 255) / 256, 256, 0, stream>>>(
            gub, ffout, S_LEN * FF_DIM / 8);

        if (l == NLAYER - 1)
            gemm64<2><<<dim3(H_DIM / 64, S_LEN / 64), 256, 0, stream>>>(
                ffout, wt + WD_OFF, d_out, x, S_LEN, H_DIM, FF_DIM, FF_DIM);
        else
            gemm64<1><<<dim3(H_DIM / 64, S_LEN / 64), 256, 0, stream>>>(
                ffout, wt + WD_OFF, x, nullptr, S_LEN, H_DIM, FF_DIM, FF_DIM);
    }
}